// Round 15
// baseline (496.289 us; speedup 1.0000x reference)
//
#include <hip/hip_runtime.h>

#define AS1 __attribute__((address_space(1)))
#define AS3 __attribute__((address_space(3)))

typedef unsigned short u16;
typedef unsigned int u32;
typedef __attribute__((ext_vector_type(8))) __bf16 bf16x8;
typedef __attribute__((ext_vector_type(8))) unsigned short u16x8;
typedef __attribute__((ext_vector_type(4))) float f32x4;

// Problem constants
#define BATCH   4
#define SEQLEN  2048
#define DMODEL  1024
#define DINNER  2048
#define DSTATE  16
#define ROWS    (BATCH * SEQLEN)   // 8192

__device__ __forceinline__ u16 f2bf(float f) {
  union { float f; unsigned u; } v; v.f = f;
  unsigned u = v.u;
  return (u16)((u + 0x7fffu + ((u >> 16) & 1u)) >> 16);   // RNE
}
__device__ __forceinline__ float bf2f(u16 s) {
  union { unsigned u; float f; } v; v.u = ((unsigned)s) << 16;
  return v.f;
}
__device__ __forceinline__ float bflo(u32 p) { union { unsigned u; float f; } v; v.u = p << 16; return v.f; }
__device__ __forceinline__ float bfhi(u32 p) { union { unsigned u; float f; } v; v.u = p & 0xffff0000u; return v.f; }

// asm ds_read_b128 with compile-time offset; address is a 32-bit LDS byte address.
template<int IMM>
__device__ __forceinline__ bf16x8 dsr(unsigned addr) {
  bf16x8 r;
  asm volatile("ds_read_b128 %0, %1 offset:%2" : "=&v"(r) : "v"(addr), "i"(IMM));
  return r;
}
__device__ __forceinline__ unsigned lds_addr(const u16* p) {
  return (unsigned)(size_t)(const AS3 u16*)p;
}
template<int N>
__device__ __forceinline__ void lgkm() {
  asm volatile("s_waitcnt lgkmcnt(%0)" :: "i"(N) : "memory");
  __builtin_amdgcn_sched_barrier(0);   // rule #18
}
template<int N>
__device__ __forceinline__ void vmw() {
  asm volatile("s_waitcnt vmcnt(%0)" :: "i"(N) : "memory");
}

// ---------------- cast f32 -> bf16 (4 elems/thread) ----------------
__global__ void cast_f32_bf16(const float* __restrict__ in, u16* __restrict__ out, int n4) {
  int i = blockIdx.x * blockDim.x + threadIdx.x;
  if (i >= n4) return;
  float4 v = ((const float4*)in)[i];
  ushort4 o;
  o.x = f2bf(v.x); o.y = f2bf(v.y); o.z = f2bf(v.z); o.w = f2bf(v.w);
  ((ushort4*)out)[i] = o;
}

// ---------------- transpose + cast: in f32 (R x C) -> out bf16 (C x R) ----------------
__global__ void transpose_cast(const float* __restrict__ in, u16* __restrict__ out, int R, int C) {
  __shared__ float tile[32][33];
  int x  = blockIdx.x * 32 + threadIdx.x;
  int y0 = blockIdx.y * 32;
#pragma unroll
  for (int j = 0; j < 32; j += 8)
    tile[threadIdx.y + j][threadIdx.x] = in[(size_t)(y0 + threadIdx.y + j) * C + x];
  __syncthreads();
  int xo  = blockIdx.y * 32 + threadIdx.x;
  int yo0 = blockIdx.x * 32;
#pragma unroll
  for (int j = 0; j < 32; j += 8)
    out[(size_t)(yo0 + threadIdx.y + j) * R + xo] = f2bf(tile[threadIdx.x][threadIdx.y + j]);
}

// ---------------- 256xBN 2-phase-per-tile bf16 MFMA GEMM, BK=32, triple buffer ----------------
// Phase = one full K-tile: {8 A-frag + NF B-frag ds_reads, stage tile t+2 (L loads)
// into buf[(t+2)%3], barrier, lgkm(0)+sched_barrier, setprio, 32/16 MFMA, counted
// vmcnt(L) (never 0 mid-loop), barrier}. Triple buffer gives 2-phase prefetch
// distance. Swizzle (both-sides, rule #21): source granule = slot ^ F(row),
// F = (row&3)^((row>>2)&3); read granule = lhi ^ (llo&3) ^ (llo>>2) -> 2-way max (free).
// Halves phase-slot count vs the R6 4-phase structure (content-invariant-cost bet).
// EPI: 0 = store bf16, 1 = softplus(v + bias[col]) -> bf16, 2 = store f32
template<int EPI, int BN_>
__launch_bounds__(512, 1)
__global__ void gemm2ph(const u16* __restrict__ A, const u16* __restrict__ Bt,
                        void* __restrict__ outp, const float* __restrict__ bias,
                        int M, int N, int K, int gn, int rr, int cc) {
  constexpr int NF   = BN_ / 64;        // 4 or 2 n-frags per wave
  constexpr int ASZ  = 256 * 32;        // u16 per A tile (16 KB)
  constexpr int BSZ  = BN_ * 32;        // u16 per B tile
  constexpr int BUFS = ASZ + BSZ;       // u16 per buffer
  constexpr int BUFB = BUFS * 2;        // bytes per buffer
  constexpr int NLB  = BN_ / 128;       // B staging loads per thread (2 or 1)
  constexpr int L    = 2 + NLB;         // total staging loads per tile per thread
  extern __shared__ u16 lds[];

  const int xcd = blockIdx.x & 7, kb = blockIdx.x >> 3;
  const int tpr = gn / cc;
  const int bm  = (xcd / tpr) * rr + kb / cc;
  const int bn  = (xcd % tpr) * cc + kb % cc;

  const int tid  = threadIdx.x;
  const int wave = tid >> 6, lane = tid & 63;
  const int wm = wave >> 2, wn = wave & 3;
  const int llo = lane & 15, lhi = lane >> 4;
  const size_t bm0 = (size_t)bm * 256, bn0 = (size_t)bn * BN_;
  const int NT = K >> 5;

  // staging sources: thread covers row = ch*128 + tid>>2, 16B slot tid&3,
  // pre-swizzled source granule = slot ^ F(row)
  const int srow = tid >> 2;
  const int fr   = ((tid >> 2) & 3) ^ ((tid >> 4) & 3);
  const int scol = ((tid & 3) ^ fr) << 3;
  const u16* gA[2];
  gA[0] = A + (bm0 + srow) * (size_t)K + scol;
  gA[1] = A + (bm0 + 128 + srow) * (size_t)K + scol;
  const u16* gB[2];
  gB[0] = Bt + (bn0 + srow) * (size_t)K + scol;
  gB[1] = (NLB == 2) ? (Bt + (bn0 + 128 + srow) * (size_t)K + scol) : gB[0];

  // ds_read base addresses (buffer 0); rotate by +BUFB per tile with wrap at 3*BUFB
  const unsigned base = lds_addr(lds);
  const unsigned gsw  = (unsigned)((lhi ^ (llo & 3) ^ (llo >> 2)) << 4);
  const unsigned rdA0 = base + (unsigned)(wm * 128 + llo) * 64u + gsw;
  const unsigned rdB0 = base + (unsigned)ASZ * 2 + (unsigned)(wn * (NF * 16) + llo) * 64u + gsw;

#define SG(t, stgoff) do {                                                        \
    __builtin_amdgcn_global_load_lds((const AS1 void*)(gA[0] + ((size_t)(t) << 5)), \
        (AS3 void*)(lds + (stgoff) + wave * 8), 16, 0, 0);                        \
    __builtin_amdgcn_global_load_lds((const AS1 void*)(gA[1] + ((size_t)(t) << 5)), \
        (AS3 void*)(lds + (stgoff) + 4096 + wave * 8), 16, 0, 0);                 \
    __builtin_amdgcn_global_load_lds((const AS1 void*)(gB[0] + ((size_t)(t) << 5)), \
        (AS3 void*)(lds + (stgoff) + ASZ + wave * 8), 16, 0, 0);                  \
    if (NLB == 2)                                                                 \
      __builtin_amdgcn_global_load_lds((const AS1 void*)(gB[1] + ((size_t)(t) << 5)), \
          (AS3 void*)(lds + (stgoff) + ASZ + 4096 + wave * 8), 16, 0, 0);         \
  } while (0)
  // note: dest per-thread = stgoff + (ch sel) + tid*8 u16; builtin adds lane*16B,
  // so pass wave-uniform base = stgoff + ch*4096 + wave*(64 lanes*8 u16)=wave*512... 
  // (wave*8 u16 would be wrong) -- fixed below by using wave*512.
#undef SG
#define SG(t, stgoff) do {                                                        \
    __builtin_amdgcn_global_load_lds((const AS1 void*)(gA[0] + ((size_t)(t) << 5)), \
        (AS3 void*)(lds + (stgoff) + wave * 512), 16, 0, 0);                      \
    __builtin_amdgcn_global_load_lds((const AS1 void*)(gA[1] + ((size_t)(t) << 5)), \
        (AS3 void*)(lds + (stgoff) + 4096 + wave * 512), 16, 0, 0);               \
    __builtin_amdgcn_global_load_lds((const AS1 void*)(gB[0] + ((size_t)(t) << 5)), \
        (AS3 void*)(lds + (stgoff) + ASZ + wave * 512), 16, 0, 0);                \
    if (NLB == 2)                                                                 \
      __builtin_amdgcn_global_load_lds((const AS1 void*)(gB[1] + ((size_t)(t) << 5)), \
          (AS3 void*)(lds + (stgoff) + ASZ + 4096 + wave * 512), 16, 0, 0);       \
  } while (0)

  f32x4 acc[8][NF] = {};

  // prologue: tile0 -> buf0, tile1 -> buf1; confirm tile0
  SG(0, 0);
  SG(1, BUFS);
  vmw<L>();
  asm volatile("s_barrier" ::: "memory");

  unsigned rdA = rdA0, rdB = rdB0;
  unsigned stg = 2 * BUFS;               // u16 offset of staging buffer (tile t+2)

  for (int t = 0; t < NT; ++t) {
    bf16x8 af[8], bf[4];
    af[0] = dsr<0>(rdA);    af[1] = dsr<1024>(rdA);
    af[2] = dsr<2048>(rdA); af[3] = dsr<3072>(rdA);
    af[4] = dsr<4096>(rdA); af[5] = dsr<5120>(rdA);
    af[6] = dsr<6144>(rdA); af[7] = dsr<7168>(rdA);
    bf[0] = dsr<0>(rdB);    bf[1] = dsr<1024>(rdB);
    if (NF == 4) { bf[2] = dsr<2048>(rdB); bf[3] = dsr<3072>(rdB); }
    const bool st = (t + 2) < NT;
    if (st) SG(t + 2, stg);
    asm volatile("s_barrier" ::: "memory");
    lgkm<0>();
    __builtin_amdgcn_s_setprio(1);
#pragma unroll
    for (int am = 0; am < 8; ++am)
#pragma unroll
      for (int n = 0; n < NF; ++n)
        acc[am][n] = __builtin_amdgcn_mfma_f32_16x16x32_bf16(af[am], bf[n], acc[am][n], 0, 0, 0);
    __builtin_amdgcn_s_setprio(0);
    if (st) vmw<L>(); else vmw<0>();
    asm volatile("s_barrier" ::: "memory");
    // rotate buffers
    rdA += BUFB; rdB += BUFB;
    if (rdA >= rdA0 + 3 * BUFB) { rdA -= 3 * BUFB; rdB -= 3 * BUFB; }
    stg += BUFS; if (stg >= 3 * BUFS) stg -= 3 * BUFS;
  }
#undef SG

  // epilogue: C mapping col = n*16+llo, row = wm*128 + mh*64 + m*16 + lhi*4 + r
#pragma unroll
  for (int am = 0; am < 8; ++am) {
    const int mh = am >> 2, m = am & 3;
    const int rowb = (int)bm0 + wm * 128 + mh * 64 + m * 16 + lhi * 4;
#pragma unroll
    for (int n = 0; n < NF; ++n) {
      const int col = (int)bn0 + wn * (16 * NF) + n * 16 + llo;
#pragma unroll
      for (int r = 0; r < 4; ++r) {
        float v = acc[am][n][r];
        size_t idx = (size_t)(rowb + r) * N + col;
        if (EPI == 0) {
          ((u16*)outp)[idx] = f2bf(v);
        } else if (EPI == 1) {
          float xb = v + bias[col];
          float sp = (xb > 20.f) ? xb : log1pf(__expf(xb));  // softplus
          ((u16*)outp)[idx] = f2bf(sp);
        } else {
          ((float*)outp)[idx] = v;
        }
      }
    }
  }
}

// ---------------- causal depthwise conv (K=4) + SiLU, 4 d per thread ----------------
__global__ void conv_silu4(const u16* __restrict__ xz, const float* __restrict__ w,
                           const float* __restrict__ cb, u16* __restrict__ xs, int total4) {
  int idx = blockIdx.x * 256 + threadIdx.x;
  if (idx >= total4) return;
  int d4 = idx & (DINNER / 4 - 1);
  int l  = (idx >> 9) & (SEQLEN - 1);
  int b  = idx >> 20;
  int d  = d4 * 4;
  float4 wv[4];
#pragma unroll
  for (int j = 0; j < 4; ++j) wv[j] = ((const float4*)w)[d + j];
  float4 bias = *(const float4*)(cb + d);
  float acc[4] = { bias.x, bias.y, bias.z, bias.w };
#pragma unroll
  for (int k = 0; k < 4; ++k) {
    int li = l - 3 + k;
    if (li >= 0) {
      ushort4 xv = *(const ushort4*)(xz + (size_t)(b * SEQLEN + li) * (2 * DINNER) + d);
      acc[0] = fmaf((&wv[0].x)[k], bf2f(xv.x), acc[0]);
      acc[1] = fmaf((&wv[1].x)[k], bf2f(xv.y), acc[1]);
      acc[2] = fmaf((&wv[2].x)[k], bf2f(xv.z), acc[2]);
      acc[3] = fmaf((&wv[3].x)[k], bf2f(xv.w), acc[3]);
    }
  }
  ushort4 o;
  o.x = f2bf(acc[0] / (1.f + __expf(-acc[0])));
  o.y = f2bf(acc[1] / (1.f + __expf(-acc[1])));
  o.z = f2bf(acc[2] / (1.f + __expf(-acc[2])));
  o.w = f2bf(acc[3] / (1.f + __expf(-acc[3])));
  *(ushort4*)(xs + (size_t)idx * 4) = o;
}

// ---------------- x-projection: xproj(ROWS x 32) = xs(ROWS x 2048) @ Wx(2048 x 32) ----------------
__global__ void xproj_kernel(const u16* __restrict__ xs, const float* __restrict__ Wx,
                             float* __restrict__ outp) {
  __shared__ float part[256];
  int row = blockIdx.x;
  int tid = threadIdx.x;
  int c = tid & 31, kp = tid >> 5;
  const u16* xr = xs + (size_t)row * DINNER + kp * 256;
  const float* wp = Wx + (size_t)(kp * 256) * 32 + c;
  float acc = 0.f;
#pragma unroll 4
  for (int kk = 0; kk < 32; ++kk) {
    u16x8 xv = *(const u16x8*)(const void*)(xr + kk * 8);
#pragma unroll
    for (int j = 0; j < 8; ++j)
      acc = fmaf(bf2f(xv[j]), wp[(kk * 8 + j) * 32], acc);
  }
  part[tid] = acc;
  __syncthreads();
  if (tid < 32) {
    float s = 0.f;
#pragma unroll
    for (int p = 0; p < 8; ++p) s += part[p * 32 + tid];
    outp[(size_t)row * 32 + tid] = s;
  }
}

// ---------------- chunked selective scan v3 (best measured) ----------------
#define SC_NC 32                // chunks
#define SC_CL 64                // steps per chunk
#define SC_LDS (2 * SC_NC * 16 * 33 * 4)   // 135168 B

__launch_bounds__(512, 1)
__global__ void scan_v3(const u16* __restrict__ delta, const u16* __restrict__ xs,
                        const float* __restrict__ xproj, const u16* __restrict__ xz,
                        const float* __restrict__ A_log, const float* __restrict__ Dp,
                        u16* __restrict__ yg) {
  extern __shared__ float smem[];
  float* cP = smem;
  float* cH = smem + SC_NC * 16 * 33;
  const int tid = threadIdx.x;
  const int dl = tid & 15, ck = tid >> 4;
  const int b = blockIdx.x >> 6, dblk = blockIdx.x & 63;
  const int d0 = dblk * 32 + dl * 2;
  const int r0 = b * SEQLEN + ck * SC_CL;

  float A0[DSTATE], A1[DSTATE];
  {
    const f32x4* ap0 = (const f32x4*)(A_log + (size_t)d0 * DSTATE);
    const f32x4* ap1 = (const f32x4*)(A_log + (size_t)(d0 + 1) * DSTATE);
#pragma unroll
    for (int q = 0; q < 4; ++q) {
      f32x4 a0 = ap0[q], a1 = ap1[q];
#pragma unroll
      for (int j = 0; j < 4; ++j) { A0[q * 4 + j] = -__expf(a0[j]); A1[q * 4 + j] = -__expf(a1[j]); }
    }
  }

  const u32* dP = (const u32*)(delta + (size_t)r0 * DINNER + d0);
  const u32* xP = (const u32*)(xs    + (size_t)r0 * DINNER + d0);
  const u32* zP = (const u32*)(xz + (size_t)r0 * (2 * DINNER) + DINNER + d0);
  const float* bP = xproj + (size_t)r0 * 32;
  const int DW = DINNER / 2;
  const int ZW = DINNER;

  float P0[DSTATE], P1[DSTATE], H0[DSTATE], H1[DSTATE];
#pragma unroll
  for (int s = 0; s < DSTATE; ++s) { P0[s] = P1[s] = 1.f; H0[s] = H1[s] = 0.f; }
  {
    u32 dq0 = dP[0], xq0 = xP[0];
    u32 dq1 = dP[DW], xq1 = xP[DW];
    f32x4 Bn[4];
#pragma unroll
    for (int q = 0; q < 4; ++q) Bn[q] = ((const f32x4*)bP)[q];
    for (int l = 0; l < SC_CL; ++l) {
      const u32 dc = dq0, xc = xq0;
      dq0 = dq1; xq0 = xq1;
      if (l + 2 < SC_CL) { dq1 = dP[(l + 2) * DW]; xq1 = xP[(l + 2) * DW]; }
      f32x4 Bc[4] = { Bn[0], Bn[1], Bn[2], Bn[3] };
      if (l + 1 < SC_CL) {
        const f32x4* bn = (const f32x4*)(bP + (l + 1) * 32);
#pragma unroll
        for (int q = 0; q < 4; ++q) Bn[q] = bn[q];
      }
      float dt0 = bflo(dc), dt1 = bfhi(dc);
      float x0 = bflo(xc),  x1 = bfhi(xc);
      float dtx0 = dt0 * x0, dtx1 = dt1 * x1;
#pragma unroll
      for (int s = 0; s < DSTATE; ++s) {
        float bs = Bc[s >> 2][s & 3];
        float dA0 = fmaf(A0[s], dt0, 1.f);
        float dA1 = fmaf(A1[s], dt1, 1.f);
        P0[s] *= dA0; P1[s] *= dA1;
        H0[s] = fmaf(H0[s], dA0, bs * dtx0);
        H1[s] = fmaf(H1[s], dA1, bs * dtx1);
      }
    }
  }
  {
    float* p = cP + (ck * 16 + dl) * 33;
    float* h = cH + (ck * 16 + dl) * 33;
#pragma unroll
    for (int s = 0; s < DSTATE; ++s) {
      p[s] = P0[s]; p[16 + s] = P1[s];
      h[s] = H0[s]; h[16 + s] = H1[s];
    }
  }
  __syncthreads();

  {
    const int s2 = tid & 15, dd = tid >> 4;
    const int idx = (dd & 1) * 16 + s2;
    float* pbase = cP + (dd >> 1) * 33 + idx;
    float* hbase = cH + (dd >> 1) * 33 + idx;
    float h = 0.f;
    for (int c = 0; c < SC_NC; ++c) {
      float p = pbase[c * 16 * 33], hh = hbase[c * 16 * 33];
      pbase[c * 16 * 33] = h;
      h = fmaf(p, h, hh);
    }
  }
  __syncthreads();

  float h0[DSTATE], h1[DSTATE];
  {
    const float* p = cP + (ck * 16 + dl) * 33;
#pragma unroll
    for (int s = 0; s < DSTATE; ++s) { h0[s] = p[s]; h1[s] = p[16 + s]; }
  }
  const float Dv0 = Dp[d0], Dv1 = Dp[d0 + 1];
  u32* yP = (u32*)(yg + (size_t)r0 * DINNER + d0);
  {
    u32 dq0 = dP[0], xq0 = xP[0], zq0 = zP[0];
    u32 dq1 = dP[DW], xq1 = xP[DW], zq1 = zP[ZW];
    f32x4 Bn[4], Cn[4];
#pragma unroll
    for (int q = 0; q < 4; ++q) { Bn[q] = ((const f32x4*)bP)[q]; Cn[q] = ((const f32x4*)bP)[q + 4]; }
    for (int l = 0; l < SC_CL; ++l) {
      const u32 dc = dq0, xc = xq0, zc = zq0;
      dq0 = dq1; xq0 = xq1; zq0 = zq1;
      if (l + 2 < SC_CL) { dq1 = dP[(l + 2) * DW]; xq1 = xP[(l + 2) * DW]; zq1 = zP[(l + 2) * ZW]; }
      f32x4 Bc[4] = { Bn[0], Bn[1], Bn[2], Bn[3] };
      f32x4 Cc[4] = { Cn[0], Cn[1], Cn[2], Cn[3] };
      if (l + 1 < SC_CL) {
        const f32x4* bn = (const f32x4*)(bP + (l + 1) * 32);
#pragma unroll
        for (int q = 0; q < 4; ++q) { Bn[q] = bn[q]; Cn[q] = bn[q + 4]; }
      }
      float dt0 = bflo(dc), dt1 = bfhi(dc);
      float x0 = bflo(xc),  x1 = bfhi(xc);
      float dtx0 = dt0 * x0, dtx1 = dt1 * x1;
      float yp0 = 0.f, yp1 = 0.f;
#pragma unroll
      for (int s = 0; s < DSTATE; ++s) {
        float bs = Bc[s >> 2][s & 3];
        float cs = Cc[s >> 2][s & 3];
        float dA0 = fmaf(A0[s], dt0, 1.f);
        float dA1 = fmaf(A1[s], dt1, 1.f);
        h0[s] = fmaf(h0[s], dA0, bs * dtx0);
        h1[s] = fmaf(h1[s], dA1, bs * dtx1);
        yp0 = fmaf(h0[s], cs, yp0);
        yp1 = fmaf(h1[s], cs, yp1);
      }
      float z0 = bflo(zc), z1 = bfhi(zc);
      float y0 = (yp0 + Dv0 * x0) * (z0 / (1.f + __expf(-z0)));
      float y1 = (yp1 + Dv1 * x1) * (z1 / (1.f + __expf(-z1)));
      yP[l * DW] = (u32)f2bf(y0) | ((u32)f2bf(y1) << 16);
    }
  }
}

extern "C" void kernel_launch(void* const* d_in, const int* in_sizes, int n_in,
                              void* d_out, int out_size, void* d_ws, size_t ws_size,
                              hipStream_t stream) {
  const float* x       = (const float*)d_in[0];
  const float* W_in    = (const float*)d_in[1];
  const float* conv_w  = (const float*)d_in[2];
  const float* conv_b  = (const float*)d_in[3];
  const float* W_xproj = (const float*)d_in[4];
  const float* W_dt    = (const float*)d_in[5];
  const float* b_dt    = (const float*)d_in[6];
  const float* A_log   = (const float*)d_in[7];
  const float* D_param = (const float*)d_in[8];
  const float* W_out   = (const float*)d_in[9];
  float* out = (float*)d_out;

  char* ws = (char*)d_ws;
  const size_t MB = 1ull << 20;
  u16*   x_bf  = (u16*)(ws);              // 16 MB   [dead after GEMM1]
  u16*   WinT  = (u16*)(ws + 16 * MB);    //  8 MB   [dead after GEMM1]
  u16*   WdtT  = (u16*)(ws + 24 * MB);    //  8 MB   [dead after GEMM2]
  u16*   xz_bf = (u16*)(ws + 32 * MB);    // 64 MB   [live through scan]
  u16*   xs_bf = (u16*)(ws + 96 * MB);    // 32 MB   [live through scan]
  u16*   delta = (u16*)(ws + 128 * MB);   // 32 MB (bf16)
  float* xpj   = (float*)(ws + 192 * MB); //  1 MB
  u16*   WoutT = (u16*)(ws + 193 * MB);   //  4 MB
  u16*   yg    = (u16*)(ws);              // 32 MB, aliases x_bf/WinT/WdtT (dead by then)

  hipFuncSetAttribute((const void*)gemm2ph<0, 256>, hipFuncAttributeMaxDynamicSharedMemorySize, 98304);
  hipFuncSetAttribute((const void*)gemm2ph<1, 256>, hipFuncAttributeMaxDynamicSharedMemorySize, 98304);
  hipFuncSetAttribute((const void*)gemm2ph<2, 128>, hipFuncAttributeMaxDynamicSharedMemorySize, 73728);
  hipFuncSetAttribute((const void*)scan_v3, hipFuncAttributeMaxDynamicSharedMemorySize, SC_LDS);

  dim3 tb(32, 8);

  // 1) casts / weight transposes
  cast_f32_bf16<<<(ROWS * DMODEL / 4 + 255) / 256, 256, 0, stream>>>(x, x_bf, ROWS * DMODEL / 4);
  transpose_cast<<<dim3((2 * DINNER) / 32, DMODEL / 32), tb, 0, stream>>>(W_in, WinT, DMODEL, 2 * DINNER);
  transpose_cast<<<dim3(DINNER / 32, DINNER / 32), tb, 0, stream>>>(W_dt, WdtT, DINNER, DINNER);
  transpose_cast<<<dim3(DMODEL / 32, DINNER / 32), tb, 0, stream>>>(W_out, WoutT, DINNER, DMODEL);

  // 2) xz = x @ W_in   (8192 x 4096, K=1024) -> bf16. grid 512, XCD tile 8x8
  gemm2ph<0, 256><<<512, 512, 98304, stream>>>(x_bf, WinT, xz_bf, nullptr,
                                               ROWS, 2 * DINNER, DMODEL, 16, 8, 8);

  // 3) xs = silu(causal_conv(xc) + conv_b) -> bf16 (4 d per thread)
  conv_silu4<<<(ROWS * DINNER / 4) / 256, 256, 0, stream>>>(
      xz_bf, conv_w, conv_b, xs_bf, ROWS * DINNER / 4);

  // 4) delta = softplus(xs @ W_dt + b_dt) (8192 x 2048, K=2048) -> bf16. grid 256, XCD tile 4x8
  gemm2ph<1, 256><<<256, 512, 98304, stream>>>(xs_bf, WdtT, delta, b_dt,
                                               ROWS, DINNER, DINNER, 8, 4, 8);

  // 5) [Bs|Cs] = xs @ W_xproj   (8192 x 32) -> f32
  xproj_kernel<<<ROWS, 256, 0, stream>>>(xs_bf, W_xproj, xpj);

  // 6) chunked selective scan v3 + D-skip + silu(z) gate -> yg bf16
  scan_v3<<<BATCH * (DINNER / 32), 512, SC_LDS, stream>>>(
      delta, xs_bf, xpj, xz_bf, A_log, D_param, yg);

  // 7) out = yg @ W_out  (8192 x 1024, K=2048) -> f32. BN=128, grid 256, XCD tile 4x8
  gemm2ph<2, 128><<<256, 512, 73728, stream>>>(yg, WoutT, out, nullptr,
                                               ROWS, DMODEL, DINNER, 8, 4, 8);
}

// Round 16
// 480.137 us; speedup vs baseline: 1.0336x; 1.0336x over previous
//
#include <hip/hip_runtime.h>

#define AS1 __attribute__((address_space(1)))
#define AS3 __attribute__((address_space(3)))

typedef unsigned short u16;
typedef unsigned int u32;
typedef __attribute__((ext_vector_type(8))) __bf16 bf16x8;
typedef __attribute__((ext_vector_type(8))) unsigned short u16x8;
typedef __attribute__((ext_vector_type(4))) float f32x4;

// Problem constants
#define BATCH   4
#define SEQLEN  2048
#define DMODEL  1024
#define DINNER  2048
#define DSTATE  16
#define ROWS    (BATCH * SEQLEN)   // 8192

__device__ __forceinline__ u16 f2bf(float f) {
  union { float f; unsigned u; } v; v.f = f;
  unsigned u = v.u;
  return (u16)((u + 0x7fffu + ((u >> 16) & 1u)) >> 16);   // RNE
}
__device__ __forceinline__ float bf2f(u16 s) {
  union { unsigned u; float f; } v; v.u = ((unsigned)s) << 16;
  return v.f;
}
__device__ __forceinline__ float bflo(u32 p) { union { unsigned u; float f; } v; v.u = p << 16; return v.f; }
__device__ __forceinline__ float bfhi(u32 p) { union { unsigned u; float f; } v; v.u = p & 0xffff0000u; return v.f; }

// asm ds_read_b128 with compile-time offset; address is a 32-bit LDS byte address.
template<int IMM>
__device__ __forceinline__ bf16x8 dsr(unsigned addr) {
  bf16x8 r;
  asm volatile("ds_read_b128 %0, %1 offset:%2" : "=&v"(r) : "v"(addr), "i"(IMM));
  return r;
}
__device__ __forceinline__ unsigned lds_addr(const u16* p) {
  return (unsigned)(size_t)(const AS3 u16*)p;
}
template<int N>
__device__ __forceinline__ void lgkm() {
  asm volatile("s_waitcnt lgkmcnt(%0)" :: "i"(N) : "memory");
  __builtin_amdgcn_sched_barrier(0);   // rule #18
}
template<int N>
__device__ __forceinline__ void vmw() {
  asm volatile("s_waitcnt vmcnt(%0)" :: "i"(N) : "memory");
}

// ---------------- cast f32 -> bf16 (4 elems/thread) ----------------
__global__ void cast_f32_bf16(const float* __restrict__ in, u16* __restrict__ out, int n4) {
  int i = blockIdx.x * blockDim.x + threadIdx.x;
  if (i >= n4) return;
  float4 v = ((const float4*)in)[i];
  ushort4 o;
  o.x = f2bf(v.x); o.y = f2bf(v.y); o.z = f2bf(v.z); o.w = f2bf(v.w);
  ((ushort4*)out)[i] = o;
}

// ---------------- transpose + cast: in f32 (R x C) -> out bf16 (C x R) ----------------
__global__ void transpose_cast(const float* __restrict__ in, u16* __restrict__ out, int R, int C) {
  __shared__ float tile[32][33];
  int x  = blockIdx.x * 32 + threadIdx.x;
  int y0 = blockIdx.y * 32;
#pragma unroll
  for (int j = 0; j < 32; j += 8)
    tile[threadIdx.y + j][threadIdx.x] = in[(size_t)(y0 + threadIdx.y + j) * C + x];
  __syncthreads();
  int xo  = blockIdx.y * 32 + threadIdx.x;
  int yo0 = blockIdx.x * 32;
#pragma unroll
  for (int j = 0; j < 32; j += 8)
    out[(size_t)(yo0 + threadIdx.y + j) * R + xo] = f2bf(tile[threadIdx.x][threadIdx.y + j]);
}

// ---------------- 128x128 fine-phase bf16 MFMA GEMM, 2 blocks/CU ----------------
// BM=BN=128, BK=64; 512 thr = 8 waves (2M x 4N); wave output 64x32 (4m x 2n frags);
// LDS 64 KB (2 x 32KB dbuf) -> 2 co-resident blocks/CU so barrier/lgkm stalls of
// one block fill under the other's MFMA (m114 TLP lever — the cell never tested).
// Per tile: 2 phases {stage t+1 at kk0-start; 6 ds_reads; bar; lgkm(0)+schedbar;
// setprio; 8 MFMA; bar}; vmcnt(0) at kk1-end (loads issued a full phase earlier).
// Overwrite invariant (R6): SG into buf^1 is issued after a barrier preceded by
// all-waves lgkm-confirm of that buffer's last reads. T2 swizzle both-sides.
// EPI: 0 = store bf16, 1 = softplus(v + bias[col]) -> bf16, 2 = store f32
template<int EPI>
__launch_bounds__(512, 4)
__global__ void gemm128d(const u16* __restrict__ A, const u16* __restrict__ Bt,
                         void* __restrict__ outp, const float* __restrict__ bias,
                         int M, int N, int K, int gn, int rr, int cc) {
  constexpr int ASZ  = 128 * 64;        // 8192 u16 = 16 KB per A tile
  constexpr int BUFS = 2 * ASZ;         // 16384 u16 = 32 KB per buffer (A+B)
  extern __shared__ u16 lds[];

  const int xcd = blockIdx.x & 7, kb = blockIdx.x >> 3;
  const int tpr = gn / cc;
  const int bm  = (xcd / tpr) * rr + kb / cc;
  const int bn  = (xcd % tpr) * cc + kb % cc;

  const int tid  = threadIdx.x;
  const int wave = tid >> 6, lane = tid & 63;
  const int wm = wave >> 2, wn = wave & 3;
  const int llo = lane & 15, lhi = lane >> 4;
  const size_t bm0 = (size_t)bm * 128, bn0 = (size_t)bn * 128;
  const int NT = K >> 6;

  // staging: chunk ch covers 64 rows, 8 threads/row; source granule pre-swizzled
  const int srow = tid >> 3;
  const int scol = ((tid & 7) ^ (srow & 7)) << 3;
  const u16* gA[2]; const u16* gB[2];
  gA[0] = A  + (bm0 + srow) * (size_t)K + scol;
  gA[1] = A  + (bm0 + 64 + srow) * (size_t)K + scol;
  gB[0] = Bt + (bn0 + srow) * (size_t)K + scol;
  gB[1] = Bt + (bn0 + 64 + srow) * (size_t)K + scol;

  // swizzled ds_read addresses: [buf][kk]
  unsigned aA[2][2], aB[2][2];
  {
    const unsigned base0 = lds_addr(lds);
    const unsigned rowA = (unsigned)(wm * 64 + llo) * 128u;
    const unsigned rowB = (unsigned)(wn * 32 + llo) * 128u;
    const unsigned msk = (unsigned)((llo & 7) << 4);
#pragma unroll
    for (int bf = 0; bf < 2; ++bf)
#pragma unroll
      for (int kk = 0; kk < 2; ++kk) {
        unsigned colk = ((unsigned)(kk * 64 + lhi * 16)) ^ msk;
        aA[bf][kk] = base0 + (unsigned)bf * (BUFS * 2) + rowA + colk;
        aB[bf][kk] = base0 + (unsigned)bf * (BUFS * 2) + (ASZ * 2) + rowB + colk;
      }
  }

#define SG(t, bsel) do {                                                          \
    __builtin_amdgcn_global_load_lds((const AS1 void*)(gA[0] + ((size_t)(t) << 6)), \
        (AS3 void*)(lds + (bsel) * BUFS + wave * 512), 16, 0, 0);                 \
    __builtin_amdgcn_global_load_lds((const AS1 void*)(gA[1] + ((size_t)(t) << 6)), \
        (AS3 void*)(lds + (bsel) * BUFS + 4096 + wave * 512), 16, 0, 0);          \
    __builtin_amdgcn_global_load_lds((const AS1 void*)(gB[0] + ((size_t)(t) << 6)), \
        (AS3 void*)(lds + (bsel) * BUFS + ASZ + wave * 512), 16, 0, 0);           \
    __builtin_amdgcn_global_load_lds((const AS1 void*)(gB[1] + ((size_t)(t) << 6)), \
        (AS3 void*)(lds + (bsel) * BUFS + ASZ + 4096 + wave * 512), 16, 0, 0);    \
  } while (0)

  f32x4 acc[4][2] = {};

  // prologue: tile 0 -> buf 0
  SG(0, 0);
  vmw<0>();
  asm volatile("s_barrier" ::: "memory");

  for (int t = 0; t < NT; ++t) {
    const int cur = t & 1;
    const bool more = (t + 1) < NT;
    // ---- phase kk0: stage t+1 into the buffer freed by tile t-1 ----
    if (more) SG(t + 1, cur ^ 1);
    {
      bf16x8 af[4], bf[2];
      af[0] = dsr<0>(aA[cur][0]);    af[1] = dsr<2048>(aA[cur][0]);
      af[2] = dsr<4096>(aA[cur][0]); af[3] = dsr<6144>(aA[cur][0]);
      bf[0] = dsr<0>(aB[cur][0]);    bf[1] = dsr<2048>(aB[cur][0]);
      asm volatile("s_barrier" ::: "memory");
      lgkm<0>();
      __builtin_amdgcn_s_setprio(1);
#pragma unroll
      for (int m = 0; m < 4; ++m)
#pragma unroll
        for (int n = 0; n < 2; ++n)
          acc[m][n] = __builtin_amdgcn_mfma_f32_16x16x32_bf16(af[m], bf[n], acc[m][n], 0, 0, 0);
      __builtin_amdgcn_s_setprio(0);
      asm volatile("s_barrier" ::: "memory");
    }
    // ---- phase kk1 ----
    {
      bf16x8 af[4], bf[2];
      af[0] = dsr<0>(aA[cur][1]);    af[1] = dsr<2048>(aA[cur][1]);
      af[2] = dsr<4096>(aA[cur][1]); af[3] = dsr<6144>(aA[cur][1]);
      bf[0] = dsr<0>(aB[cur][1]);    bf[1] = dsr<2048>(aB[cur][1]);
      asm volatile("s_barrier" ::: "memory");
      lgkm<0>();
      __builtin_amdgcn_s_setprio(1);
#pragma unroll
      for (int m = 0; m < 4; ++m)
#pragma unroll
        for (int n = 0; n < 2; ++n)
          acc[m][n] = __builtin_amdgcn_mfma_f32_16x16x32_bf16(af[m], bf[n], acc[m][n], 0, 0, 0);
      __builtin_amdgcn_s_setprio(0);
      vmw<0>();   // tile t+1 landed (issued at kk0-start, a full phase ago)
      asm volatile("s_barrier" ::: "memory");
    }
  }
#undef SG

  // epilogue: C mapping col = n*16+llo, row = wm*64 + m*16 + lhi*4 + r
#pragma unroll
  for (int m = 0; m < 4; ++m) {
    const int rowb = (int)bm0 + wm * 64 + m * 16 + lhi * 4;
#pragma unroll
    for (int n = 0; n < 2; ++n) {
      const int col = (int)bn0 + wn * 32 + n * 16 + llo;
#pragma unroll
      for (int r = 0; r < 4; ++r) {
        float v = acc[m][n][r];
        size_t idx = (size_t)(rowb + r) * N + col;
        if (EPI == 0) {
          ((u16*)outp)[idx] = f2bf(v);
        } else if (EPI == 1) {
          float xb = v + bias[col];
          float sp = (xb > 20.f) ? xb : log1pf(__expf(xb));  // softplus
          ((u16*)outp)[idx] = f2bf(sp);
        } else {
          ((float*)outp)[idx] = v;
        }
      }
    }
  }
}

// ---------------- causal depthwise conv (K=4) + SiLU, 4 d per thread ----------------
__global__ void conv_silu4(const u16* __restrict__ xz, const float* __restrict__ w,
                           const float* __restrict__ cb, u16* __restrict__ xs, int total4) {
  int idx = blockIdx.x * 256 + threadIdx.x;
  if (idx >= total4) return;
  int d4 = idx & (DINNER / 4 - 1);
  int l  = (idx >> 9) & (SEQLEN - 1);
  int b  = idx >> 20;
  int d  = d4 * 4;
  float4 wv[4];
#pragma unroll
  for (int j = 0; j < 4; ++j) wv[j] = ((const float4*)w)[d + j];
  float4 bias = *(const float4*)(cb + d);
  float acc[4] = { bias.x, bias.y, bias.z, bias.w };
#pragma unroll
  for (int k = 0; k < 4; ++k) {
    int li = l - 3 + k;
    if (li >= 0) {
      ushort4 xv = *(const ushort4*)(xz + (size_t)(b * SEQLEN + li) * (2 * DINNER) + d);
      acc[0] = fmaf((&wv[0].x)[k], bf2f(xv.x), acc[0]);
      acc[1] = fmaf((&wv[1].x)[k], bf2f(xv.y), acc[1]);
      acc[2] = fmaf((&wv[2].x)[k], bf2f(xv.z), acc[2]);
      acc[3] = fmaf((&wv[3].x)[k], bf2f(xv.w), acc[3]);
    }
  }
  ushort4 o;
  o.x = f2bf(acc[0] / (1.f + __expf(-acc[0])));
  o.y = f2bf(acc[1] / (1.f + __expf(-acc[1])));
  o.z = f2bf(acc[2] / (1.f + __expf(-acc[2])));
  o.w = f2bf(acc[3] / (1.f + __expf(-acc[3])));
  *(ushort4*)(xs + (size_t)idx * 4) = o;
}

// ---------------- x-projection: xproj(ROWS x 32) = xs(ROWS x 2048) @ Wx(2048 x 32) ----------------
__global__ void xproj_kernel(const u16* __restrict__ xs, const float* __restrict__ Wx,
                             float* __restrict__ outp) {
  __shared__ float part[256];
  int row = blockIdx.x;
  int tid = threadIdx.x;
  int c = tid & 31, kp = tid >> 5;
  const u16* xr = xs + (size_t)row * DINNER + kp * 256;
  const float* wp = Wx + (size_t)(kp * 256) * 32 + c;
  float acc = 0.f;
#pragma unroll 4
  for (int kk = 0; kk < 32; ++kk) {
    u16x8 xv = *(const u16x8*)(const void*)(xr + kk * 8);
#pragma unroll
    for (int j = 0; j < 8; ++j)
      acc = fmaf(bf2f(xv[j]), wp[(kk * 8 + j) * 32], acc);
  }
  part[tid] = acc;
  __syncthreads();
  if (tid < 32) {
    float s = 0.f;
#pragma unroll
    for (int p = 0; p < 8; ++p) s += part[p * 32 + tid];
    outp[(size_t)row * 32 + tid] = s;
  }
}

// ---------------- chunked selective scan v3 (best measured) ----------------
#define SC_NC 32                // chunks
#define SC_CL 64                // steps per chunk
#define SC_LDS (2 * SC_NC * 16 * 33 * 4)   // 135168 B

__launch_bounds__(512, 1)
__global__ void scan_v3(const u16* __restrict__ delta, const u16* __restrict__ xs,
                        const float* __restrict__ xproj, const u16* __restrict__ xz,
                        const float* __restrict__ A_log, const float* __restrict__ Dp,
                        u16* __restrict__ yg) {
  extern __shared__ float smem[];
  float* cP = smem;
  float* cH = smem + SC_NC * 16 * 33;
  const int tid = threadIdx.x;
  const int dl = tid & 15, ck = tid >> 4;
  const int b = blockIdx.x >> 6, dblk = blockIdx.x & 63;
  const int d0 = dblk * 32 + dl * 2;
  const int r0 = b * SEQLEN + ck * SC_CL;

  float A0[DSTATE], A1[DSTATE];
  {
    const f32x4* ap0 = (const f32x4*)(A_log + (size_t)d0 * DSTATE);
    const f32x4* ap1 = (const f32x4*)(A_log + (size_t)(d0 + 1) * DSTATE);
#pragma unroll
    for (int q = 0; q < 4; ++q) {
      f32x4 a0 = ap0[q], a1 = ap1[q];
#pragma unroll
      for (int j = 0; j < 4; ++j) { A0[q * 4 + j] = -__expf(a0[j]); A1[q * 4 + j] = -__expf(a1[j]); }
    }
  }

  const u32* dP = (const u32*)(delta + (size_t)r0 * DINNER + d0);
  const u32* xP = (const u32*)(xs    + (size_t)r0 * DINNER + d0);
  const u32* zP = (const u32*)(xz + (size_t)r0 * (2 * DINNER) + DINNER + d0);
  const float* bP = xproj + (size_t)r0 * 32;
  const int DW = DINNER / 2;
  const int ZW = DINNER;

  float P0[DSTATE], P1[DSTATE], H0[DSTATE], H1[DSTATE];
#pragma unroll
  for (int s = 0; s < DSTATE; ++s) { P0[s] = P1[s] = 1.f; H0[s] = H1[s] = 0.f; }
  {
    u32 dq0 = dP[0], xq0 = xP[0];
    u32 dq1 = dP[DW], xq1 = xP[DW];
    f32x4 Bn[4];
#pragma unroll
    for (int q = 0; q < 4; ++q) Bn[q] = ((const f32x4*)bP)[q];
    for (int l = 0; l < SC_CL; ++l) {
      const u32 dc = dq0, xc = xq0;
      dq0 = dq1; xq0 = xq1;
      if (l + 2 < SC_CL) { dq1 = dP[(l + 2) * DW]; xq1 = xP[(l + 2) * DW]; }
      f32x4 Bc[4] = { Bn[0], Bn[1], Bn[2], Bn[3] };
      if (l + 1 < SC_CL) {
        const f32x4* bn = (const f32x4*)(bP + (l + 1) * 32);
#pragma unroll
        for (int q = 0; q < 4; ++q) Bn[q] = bn[q];
      }
      float dt0 = bflo(dc), dt1 = bfhi(dc);
      float x0 = bflo(xc),  x1 = bfhi(xc);
      float dtx0 = dt0 * x0, dtx1 = dt1 * x1;
#pragma unroll
      for (int s = 0; s < DSTATE; ++s) {
        float bs = Bc[s >> 2][s & 3];
        float dA0 = fmaf(A0[s], dt0, 1.f);
        float dA1 = fmaf(A1[s], dt1, 1.f);
        P0[s] *= dA0; P1[s] *= dA1;
        H0[s] = fmaf(H0[s], dA0, bs * dtx0);
        H1[s] = fmaf(H1[s], dA1, bs * dtx1);
      }
    }
  }
  {
    float* p = cP + (ck * 16 + dl) * 33;
    float* h = cH + (ck * 16 + dl) * 33;
#pragma unroll
    for (int s = 0; s < DSTATE; ++s) {
      p[s] = P0[s]; p[16 + s] = P1[s];
      h[s] = H0[s]; h[16 + s] = H1[s];
    }
  }
  __syncthreads();

  {
    const int s2 = tid & 15, dd = tid >> 4;
    const int idx = (dd & 1) * 16 + s2;
    float* pbase = cP + (dd >> 1) * 33 + idx;
    float* hbase = cH + (dd >> 1) * 33 + idx;
    float h = 0.f;
    for (int c = 0; c < SC_NC; ++c) {
      float p = pbase[c * 16 * 33], hh = hbase[c * 16 * 33];
      pbase[c * 16 * 33] = h;
      h = fmaf(p, h, hh);
    }
  }
  __syncthreads();

  float h0[DSTATE], h1[DSTATE];
  {
    const float* p = cP + (ck * 16 + dl) * 33;
#pragma unroll
    for (int s = 0; s < DSTATE; ++s) { h0[s] = p[s]; h1[s] = p[16 + s]; }
  }
  const float Dv0 = Dp[d0], Dv1 = Dp[d0 + 1];
  u32* yP = (u32*)(yg + (size_t)r0 * DINNER + d0);
  {
    u32 dq0 = dP[0], xq0 = xP[0], zq0 = zP[0];
    u32 dq1 = dP[DW], xq1 = xP[DW], zq1 = zP[ZW];
    f32x4 Bn[4], Cn[4];
#pragma unroll
    for (int q = 0; q < 4; ++q) { Bn[q] = ((const f32x4*)bP)[q]; Cn[q] = ((const f32x4*)bP)[q + 4]; }
    for (int l = 0; l < SC_CL; ++l) {
      const u32 dc = dq0, xc = xq0, zc = zq0;
      dq0 = dq1; xq0 = xq1; zq0 = zq1;
      if (l + 2 < SC_CL) { dq1 = dP[(l + 2) * DW]; xq1 = xP[(l + 2) * DW]; zq1 = zP[(l + 2) * ZW]; }
      f32x4 Bc[4] = { Bn[0], Bn[1], Bn[2], Bn[3] };
      f32x4 Cc[4] = { Cn[0], Cn[1], Cn[2], Cn[3] };
      if (l + 1 < SC_CL) {
        const f32x4* bn = (const f32x4*)(bP + (l + 1) * 32);
#pragma unroll
        for (int q = 0; q < 4; ++q) { Bn[q] = bn[q]; Cn[q] = bn[q + 4]; }
      }
      float dt0 = bflo(dc), dt1 = bfhi(dc);
      float x0 = bflo(xc),  x1 = bfhi(xc);
      float dtx0 = dt0 * x0, dtx1 = dt1 * x1;
      float yp0 = 0.f, yp1 = 0.f;
#pragma unroll
      for (int s = 0; s < DSTATE; ++s) {
        float bs = Bc[s >> 2][s & 3];
        float cs = Cc[s >> 2][s & 3];
        float dA0 = fmaf(A0[s], dt0, 1.f);
        float dA1 = fmaf(A1[s], dt1, 1.f);
        h0[s] = fmaf(h0[s], dA0, bs * dtx0);
        h1[s] = fmaf(h1[s], dA1, bs * dtx1);
        yp0 = fmaf(h0[s], cs, yp0);
        yp1 = fmaf(h1[s], cs, yp1);
      }
      float z0 = bflo(zc), z1 = bfhi(zc);
      float y0 = (yp0 + Dv0 * x0) * (z0 / (1.f + __expf(-z0)));
      float y1 = (yp1 + Dv1 * x1) * (z1 / (1.f + __expf(-z1)));
      yP[l * DW] = (u32)f2bf(y0) | ((u32)f2bf(y1) << 16);
    }
  }
}

extern "C" void kernel_launch(void* const* d_in, const int* in_sizes, int n_in,
                              void* d_out, int out_size, void* d_ws, size_t ws_size,
                              hipStream_t stream) {
  const float* x       = (const float*)d_in[0];
  const float* W_in    = (const float*)d_in[1];
  const float* conv_w  = (const float*)d_in[2];
  const float* conv_b  = (const float*)d_in[3];
  const float* W_xproj = (const float*)d_in[4];
  const float* W_dt    = (const float*)d_in[5];
  const float* b_dt    = (const float*)d_in[6];
  const float* A_log   = (const float*)d_in[7];
  const float* D_param = (const float*)d_in[8];
  const float* W_out   = (const float*)d_in[9];
  float* out = (float*)d_out;

  char* ws = (char*)d_ws;
  const size_t MB = 1ull << 20;
  u16*   x_bf  = (u16*)(ws);              // 16 MB   [dead after GEMM1]
  u16*   WinT  = (u16*)(ws + 16 * MB);    //  8 MB   [dead after GEMM1]
  u16*   WdtT  = (u16*)(ws + 24 * MB);    //  8 MB   [dead after GEMM2]
  u16*   xz_bf = (u16*)(ws + 32 * MB);    // 64 MB   [live through scan]
  u16*   xs_bf = (u16*)(ws + 96 * MB);    // 32 MB   [live through scan]
  u16*   delta = (u16*)(ws + 128 * MB);   // 32 MB (bf16)
  float* xpj   = (float*)(ws + 192 * MB); //  1 MB
  u16*   WoutT = (u16*)(ws + 193 * MB);   //  4 MB
  u16*   yg    = (u16*)(ws);              // 32 MB, aliases x_bf/WinT/WdtT (dead by then)

  hipFuncSetAttribute((const void*)gemm128d<0>, hipFuncAttributeMaxDynamicSharedMemorySize, 65536);
  hipFuncSetAttribute((const void*)gemm128d<1>, hipFuncAttributeMaxDynamicSharedMemorySize, 65536);
  hipFuncSetAttribute((const void*)gemm128d<2>, hipFuncAttributeMaxDynamicSharedMemorySize, 65536);
  hipFuncSetAttribute((const void*)scan_v3, hipFuncAttributeMaxDynamicSharedMemorySize, SC_LDS);

  dim3 tb(32, 8);

  // 1) casts / weight transposes
  cast_f32_bf16<<<(ROWS * DMODEL / 4 + 255) / 256, 256, 0, stream>>>(x, x_bf, ROWS * DMODEL / 4);
  transpose_cast<<<dim3((2 * DINNER) / 32, DMODEL / 32), tb, 0, stream>>>(W_in, WinT, DMODEL, 2 * DINNER);
  transpose_cast<<<dim3(DINNER / 32, DINNER / 32), tb, 0, stream>>>(W_dt, WdtT, DINNER, DINNER);
  transpose_cast<<<dim3(DMODEL / 32, DINNER / 32), tb, 0, stream>>>(W_out, WoutT, DINNER, DMODEL);

  // 2) xz = x @ W_in   (8192 x 4096, K=1024). grid 2048 (8/CU, 2 co-res); XCD 32x8 (2x4)
  gemm128d<0><<<2048, 512, 65536, stream>>>(x_bf, WinT, xz_bf, nullptr,
                                            ROWS, 2 * DINNER, DMODEL, 32, 32, 8);

  // 3) xs = silu(causal_conv(xc) + conv_b) -> bf16 (4 d per thread)
  conv_silu4<<<(ROWS * DINNER / 4) / 256, 256, 0, stream>>>(
      xz_bf, conv_w, conv_b, xs_bf, ROWS * DINNER / 4);

  // 4) delta = softplus(xs @ W_dt + b_dt) (8192 x 2048, K=2048). grid 1024; XCD 32x4 (2x4)
  gemm128d<1><<<1024, 512, 65536, stream>>>(xs_bf, WdtT, delta, b_dt,
                                            ROWS, DINNER, DINNER, 16, 32, 4);

  // 5) [Bs|Cs] = xs @ W_xproj   (8192 x 32) -> f32
  xproj_kernel<<<ROWS, 256, 0, stream>>>(xs_bf, W_xproj, xpj);

  // 6) chunked selective scan v3 + D-skip + silu(z) gate -> yg bf16
  scan_v3<<<BATCH * (DINNER / 32), 512, SC_LDS, stream>>>(
      delta, xs_bf, xpj, xz_bf, A_log, D_param, yg);

  // 7) out = yg @ W_out  (8192 x 1024, K=2048). grid 512 (2/CU, 1 round!); XCD 16x4 (4x2)
  gemm128d<2><<<512, 512, 65536, stream>>>(yg, WoutT, out, nullptr,
                                           ROWS, DMODEL, DINNER, 8, 16, 4);
}